// Round 3
// baseline (5088.888 us; speedup 1.0000x reference)
//
#include <hip/hip_runtime.h>

// Problem constants
#define VV 10000
#define DD 512
#define HH 8
#define DH 64
#define DI 2048
#define LL 12
#define BB 4
#define SS 1024
#define TT (BB * SS)   // 4096 tokens

// All GEMMs and attention on matrix cores via split-bf16:
// x = hi + lo (both bf16), A*B ~= Ah*Bh + Ah*Bl + Al*Bh, fp32 MFMA accum.
// Round 3: global_load_lds(width=16) staging everywhere (pre-swizzled
// source, linear LDS dest - guide caveat #21), serpentine n-chunk XCD
// swizzle for the logits GEMM, setprio around flash MFMA clusters.

typedef __attribute__((ext_vector_type(8))) short bhalf8;    // 8 bf16 = 4 VGPRs
typedef __attribute__((ext_vector_type(16))) float f32x16;   // MFMA 32x32 accum

// async global->LDS, 16B per lane; dest is wave-uniform base + lane*16
__device__ __forceinline__ void gload16(const unsigned short* g, void* l)
{
    __builtin_amdgcn_global_load_lds(
        (const __attribute__((address_space(1))) void*)g,
        (__attribute__((address_space(3))) void*)l, 16, 0, 0);
}

// RNE split of fp32 into bf16 hi + bf16 lo.
__device__ __forceinline__ void split_bf16(float x, unsigned short& h, unsigned short& l)
{
    unsigned int u = __float_as_uint(x);
    unsigned int r = (u + 0x7FFFu + ((u >> 16) & 1u)) & 0xFFFF0000u;
    h = (unsigned short)(r >> 16);
    float lf = x - __uint_as_float(r);          // exact (Sterbenz-range)
    unsigned int ul = __float_as_uint(lf);
    l = (unsigned short)((ul + 0x7FFFu + ((ul >> 16) & 1u)) >> 16);
}

// ---------------------------------------------------------------------------
// fp32 -> (bf16 hi, bf16 lo) bulk converter. n4 = element count / 4.
// ---------------------------------------------------------------------------
__global__ __launch_bounds__(256) void convsplit(
    const float* __restrict__ src, unsigned short* __restrict__ hi,
    unsigned short* __restrict__ lo, int n4)
{
    int stride = gridDim.x * 256;
    for (int i = blockIdx.x * 256 + threadIdx.x; i < n4; i += stride) {
        float4 v = ((const float4*)src)[i];
        ushort4 h, l;
        split_bf16(v.x, h.x, l.x);
        split_bf16(v.y, h.y, l.y);
        split_bf16(v.z, h.z, l.z);
        split_bf16(v.w, h.w, l.w);
        ((ushort4*)hi)[i] = h;
        ((ushort4*)lo)[i] = l;
    }
}

// ---------------------------------------------------------------------------
// Embedding: h = word_emb[data] + pos_emb ; also emits bf16 hi/lo pair.
// ---------------------------------------------------------------------------
__global__ __launch_bounds__(256) void embed_kernel(
    const int* __restrict__ data, const float* __restrict__ we,
    const float* __restrict__ pe, float* __restrict__ h,
    unsigned short* __restrict__ hhi, unsigned short* __restrict__ hlo)
{
    int tok = blockIdx.x;
    int tid = threadIdx.x;
    int idx = data[tok];
    int s = tok & (SS - 1);
    size_t base = (size_t)tok * DD;
    size_t wb = (size_t)idx * DD;
    size_t pb = (size_t)s * DD;
    float a = we[wb + tid] + pe[pb + tid];
    float b = we[wb + 256 + tid] + pe[pb + 256 + tid];
    h[base + tid] = a;
    h[base + 256 + tid] = b;
    unsigned short hx, lx;
    split_bf16(a, hx, lx); hhi[base + tid] = hx;       hlo[base + tid] = lx;
    split_bf16(b, hx, lx); hhi[base + 256 + tid] = hx; hlo[base + 256 + tid] = lx;
}

// ---------------------------------------------------------------------------
// Split-bf16 MFMA GEMM: C[M,N] = A[M,K] * W[N,K]^T (+bias)(+relu)
// Block tile 128 x BN, 4 waves (2x2), wave tile 64 x BN/2,
// fragments 32x32 via v_mfma_f32_32x32x16_bf16 (3 MFMA per fragment pair).
// LDS layout (unchanged from round 2): A-hi 16K | A-lo 16K | B-hi BT | B-lo BT,
// within each: byte = slot*(rows*16) + ((row^slot)<<4). Staging now uses
// global_load_lds: LDS window w (1024B, dest = w*1024 linear) pulls, per
// lane, the chunk whose swizzled position equals the linear slot - i.e.
// row = chunk ^ slot computed on the GLOBAL source side (m173 pattern).
// EPI: 0 fp32, 1 fp32+bias, 2 bias+relu->pair, 3 pair,
//      4 kv: n<512 -> K pair [m][512]; n>=512 -> Vt pair [(n-512)*TT + m].
// SWZ: serpentine n-chunk XCD remap - ONLY valid for grid (79,32) (logits).
// ---------------------------------------------------------------------------
template<int BN, int EPI, bool SWZ>
__global__ __launch_bounds__(256) void gemm_mfma(
    const unsigned short* __restrict__ Ahp, const unsigned short* __restrict__ Alp,
    const unsigned short* __restrict__ Whp, const unsigned short* __restrict__ Wlp,
    const float* __restrict__ bias, float* __restrict__ C,
    unsigned short* __restrict__ Chp, unsigned short* __restrict__ Clp,
    unsigned short* __restrict__ Vhp, unsigned short* __restrict__ Vlp,
    int N, int K)
{
    constexpr int FN  = BN / 64;           // n-fragments per wave
    constexpr int BT  = BN * 128;          // bytes per B tile (8 slots * BN * 16)
    constexpr int NWB = BN / 8;            // 1KB windows per B buffer
    constexpr int NW  = 32 + 2 * NWB;      // total windows per K-step
    constexpr int WPW = NW / 4;            // windows per wave
    __shared__ __align__(16) char smem[32768 + 2 * BT];  // Ah|Al|Bh|Bl

    int bx = blockIdx.x, by = blockIdx.y;
    if (SWZ) {
        // grid = (79, 32). XCD residue class x gets t in [x*316, x*316+316):
        // serpentine order = for n-chunk c (7x10 + 1x9 panels): for band in 32:
        // for panel in chunk. W chunk (~2.6 MB pair) stays L2-resident per XCD.
        int id = by * 79 + bx;
        int t  = (id & 7) * 316 + (id >> 3);
        if (t < 2240) { int c = t / 320, r = t - c * 320; by = r / 10; bx = c * 10 + r % 10; }
        else          { int r = t - 2240;                 by = r / 9;  bx = 70 + r % 9; }
    }

    const int tid   = threadIdx.x;
    const int lane  = tid & 63;
    const int wid   = tid >> 6;
    const int wm    = wid >> 1;
    const int wn    = wid & 1;
    const int laneM = lane & 31;
    const int laneK = lane >> 5;
    const int m0    = by * 128;
    const int n0    = bx * BN;

    // Per-window pre-swizzled global source (k-invariant part).
    // LDS dest for window w is simply smem + w*1024 (regions are contiguous).
    const unsigned short* wsrc[WPW];
    #pragma unroll
    for (int t = 0; t < WPW; ++t) {
        int w = wid * WPW + t;
        if (w < 32) {                       // A: windows 0-15 hi, 16-31 lo
            const unsigned short* bp = (w < 16) ? Ahp : Alp;
            int wa = w & 15;
            int slot = wa >> 1;
            int row = (((wa & 1) << 6) | lane) ^ slot;
            wsrc[t] = bp + (size_t)(m0 + row) * K + slot * 8;
        } else {                            // B: NWB windows hi, NWB lo
            int d = w - 32;
            const unsigned short* bp = (d < NWB) ? Whp : Wlp;
            int wb = d & (NWB - 1);
            int slot, row;
            if (BN == 64) { slot = wb;      row = lane ^ slot; }
            else          { slot = wb >> 1; row = (((wb & 1) << 6) | lane) ^ slot; }
            int n = n0 + row;
            n = (n < N) ? n : (N - 1);      // clamp (logits tail); stores guarded
            wsrc[t] = bp + (size_t)n * K + slot * 8;
        }
    }

    f32x16 acc[2][FN];
    #pragma unroll
    for (int i = 0; i < 2; ++i)
        #pragma unroll
        for (int j = 0; j < FN; ++j)
            #pragma unroll
            for (int r = 0; r < 16; ++r) acc[i][j][r] = 0.f;

    for (int k0 = 0; k0 < K; k0 += 64) {
        __syncthreads();                   // previous tile's reads complete
        #pragma unroll
        for (int t = 0; t < WPW; ++t)
            gload16(wsrc[t] + k0, smem + (wid * WPW + t) * 1024);
        __syncthreads();                   // drains vmcnt -> staging visible

        #pragma unroll
        for (int kb = 0; kb < 4; ++kb) {   // 4 x (k=16) per K-step
            const int slot = kb * 2 + laneK;
            bhalf8 ah[2], al[2], bh[FN], bl[FN];
            #pragma unroll
            for (int i = 0; i < 2; ++i) {
                int row = wm * 64 + i * 32 + laneM;
                int off = slot * 2048 + ((row ^ slot) << 4);
                ah[i] = *(const bhalf8*)(smem + off);
                al[i] = *(const bhalf8*)(smem + 16384 + off);
            }
            #pragma unroll
            for (int j = 0; j < FN; ++j) {
                int row = wn * (BN / 2) + j * 32 + laneM;
                int off = 32768 + slot * (BN * 16) + ((row ^ slot) << 4);
                bh[j] = *(const bhalf8*)(smem + off);
                bl[j] = *(const bhalf8*)(smem + BT + off);
            }
            #pragma unroll
            for (int i = 0; i < 2; ++i)
                #pragma unroll
                for (int j = 0; j < FN; ++j) {
                    acc[i][j] = __builtin_amdgcn_mfma_f32_32x32x16_bf16(ah[i], bh[j], acc[i][j], 0, 0, 0);
                    acc[i][j] = __builtin_amdgcn_mfma_f32_32x32x16_bf16(ah[i], bl[j], acc[i][j], 0, 0, 0);
                    acc[i][j] = __builtin_amdgcn_mfma_f32_32x32x16_bf16(al[i], bh[j], acc[i][j], 0, 0, 0);
                }
        }
    }

    // Epilogue. C/D layout: col = lane&31, row = (r&3)+8*(r>>2)+4*laneK
    #pragma unroll
    for (int j = 0; j < FN; ++j) {
        int ncol = n0 + wn * (BN / 2) + j * 32 + laneM;
        bool nok = (ncol < N);
        float bv = 0.f;
        if (EPI == 1 || EPI == 2) { if (nok) bv = bias[ncol]; }
        #pragma unroll
        for (int i = 0; i < 2; ++i) {
            #pragma unroll
            for (int r = 0; r < 16; ++r) {
                int mrow = m0 + wm * 64 + i * 32 + (r & 3) + ((r >> 2) << 3) + laneK * 4;
                float v = acc[i][j][r] + bv;
                if (EPI == 2) v = fmaxf(v, 0.f);
                if (nok) {
                    if (EPI == 2 || EPI == 3) {
                        unsigned short hx, lx;
                        split_bf16(v, hx, lx);
                        Chp[(size_t)mrow * N + ncol] = hx;
                        Clp[(size_t)mrow * N + ncol] = lx;
                    } else if (EPI == 4) {
                        unsigned short hx, lx;
                        split_bf16(v, hx, lx);
                        if (ncol < 512) {
                            Chp[(size_t)mrow * 512 + ncol] = hx;
                            Clp[(size_t)mrow * 512 + ncol] = lx;
                        } else {
                            Vhp[(size_t)(ncol - 512) * TT + mrow] = hx;
                            Vlp[(size_t)(ncol - 512) * TT + mrow] = lx;
                        }
                    } else {
                        C[(size_t)mrow * N + ncol] = v;
                    }
                }
            }
        }
    }
}

// ---------------------------------------------------------------------------
// MFMA flash attention (split-bf16, causal). One block = 64 q-rows x (head,b),
// 128 threads = 2 waves; wave wq owns q-rows [32*wq, 32*wq+32).
// Swapped QK^T: s = mfma(K, Q) -> C[key][q]; softmax per-lane + 1 shfl.
// K/Vt tiles staged via global_load_lds with pre-swizzled source: LDS byte
// o = row*128 + ((64*half+16*j) ^ ((row&7)<<4)); inverse on source side:
// row = o>>7, elem = ((o&127) ^ ((row&7)<<4)) >> 1. Wave 0 stages K hi/lo,
// wave 1 stages Vt hi/lo (8 windows each buffer).
// ---------------------------------------------------------------------------
__global__ __launch_bounds__(128) void flash_mfma(
    const unsigned short* __restrict__ qhp, const unsigned short* __restrict__ qlp,
    const unsigned short* __restrict__ khp, const unsigned short* __restrict__ klp,
    const unsigned short* __restrict__ vthp, const unsigned short* __restrict__ vtlp,
    unsigned short* __restrict__ avh, unsigned short* __restrict__ avl)
{
    __shared__ __align__(16) char lds[50176];   // K 16K | Vt 16K | P 2x8704

    const int qt  = 15 - (int)blockIdx.x;       // heavy q-tiles first
    const int hh  = blockIdx.y;
    const int b   = blockIdx.z;
    const int tid = threadIdx.x;
    const int lane  = tid & 63;
    const int wq    = tid >> 6;
    const int laneM = lane & 31;
    const int laneK = lane >> 5;
    const int q0    = qt * 64;

    // Q fragments (B-operand): col q = laneM, k(d) = 16*ks + 8*laneK + i
    bhalf8 Qh[4], Ql[4];
    {
        size_t qoff = (size_t)(b * SS + q0 + 32 * wq + laneM) * 512 + hh * 64 + 8 * laneK;
        #pragma unroll
        for (int ks = 0; ks < 4; ++ks) {
            Qh[ks] = *(const bhalf8*)(qhp + qoff + 16 * ks);
            Ql[ks] = *(const bhalf8*)(qlp + qoff + 16 * ks);
        }
    }

    f32x16 O0, O1;                              // O^T frags: d-blocks 0,1
    #pragma unroll
    for (int r = 0; r < 16; ++r) { O0[r] = 0.f; O1[r] = 0.f; }
    float mrun = -1e30f, lrun = 0.f;            // per-lane (q = laneM)

    float* Pl = (float*)(lds + 32768 + wq * 8704);   // [32 q][68]
    const unsigned short* shi = wq ? vthp : khp;
    const unsigned short* slo = wq ? vtlp : klp;
    char* dbase = lds + wq * 16384;

    for (int kt = 0; kt <= qt; ++kt) {
        __syncthreads();                        // prev-tile LDS reads done
        #pragma unroll
        for (int t = 0; t < 8; ++t) {
            int o   = t * 1024 + lane * 16;
            int row = o >> 7;
            int eo  = ((o & 127) ^ ((row & 7) << 4)) >> 1;
            size_t rb = wq ? ((size_t)(hh * 64 + row) * TT + (size_t)b * SS + kt * 64)
                           : ((size_t)(b * SS + kt * 64 + row) * 512 + hh * 64);
            gload16(shi + rb + eo, dbase + t * 1024);
            gload16(slo + rb + eo, dbase + 8192 + t * 1024);
        }
        __syncthreads();                        // tiles staged

        // S^T = K Q^T  (frag s0: keys 0-31, s1: keys 32-63; col = q)
        f32x16 s0, s1;
        #pragma unroll
        for (int r = 0; r < 16; ++r) { s0[r] = 0.f; s1[r] = 0.f; }
        __builtin_amdgcn_s_setprio(1);
        #pragma unroll
        for (int ks = 0; ks < 4; ++ks) {
            int db = 32 * ks + 16 * laneK;
            int o0 = (laneM * 128 + db) ^ ((laneM & 7) << 4);
            int r1 = 32 + laneM;
            int o1 = (r1 * 128 + db) ^ ((r1 & 7) << 4);
            bhalf8 kh0 = *(const bhalf8*)(lds + o0);
            bhalf8 kl0 = *(const bhalf8*)(lds + 8192 + o0);
            bhalf8 kh1 = *(const bhalf8*)(lds + o1);
            bhalf8 kl1 = *(const bhalf8*)(lds + 8192 + o1);
            s0 = __builtin_amdgcn_mfma_f32_32x32x16_bf16(kh0, Qh[ks], s0, 0, 0, 0);
            s0 = __builtin_amdgcn_mfma_f32_32x32x16_bf16(kh0, Ql[ks], s0, 0, 0, 0);
            s0 = __builtin_amdgcn_mfma_f32_32x32x16_bf16(kl0, Qh[ks], s0, 0, 0, 0);
            s1 = __builtin_amdgcn_mfma_f32_32x32x16_bf16(kh1, Qh[ks], s1, 0, 0, 0);
            s1 = __builtin_amdgcn_mfma_f32_32x32x16_bf16(kh1, Ql[ks], s1, 0, 0, 0);
            s1 = __builtin_amdgcn_mfma_f32_32x32x16_bf16(kl1, Qh[ks], s1, 0, 0, 0);
        }
        __builtin_amdgcn_s_setprio(0);

        #pragma unroll
        for (int r = 0; r < 16; ++r) { s0[r] *= 0.125f; s1[r] *= 0.125f; }

        if (kt == qt) {                         // causal mask on diagonal tile
            int qrel = 32 * wq + laneM;
            #pragma unroll
            for (int r = 0; r < 16; ++r) {
                int krel = (r & 3) + ((r >> 2) << 3) + 4 * laneK;
                if (krel > qrel)      s0[r] = -1e30f;
                if (krel + 32 > qrel) s1[r] = -1e30f;
            }
        }

        // online softmax, per-lane scalars (lane = one q-row, 32 of 64 keys;
        // partner lane^32 holds the other 32)
        float mx = s0[0];
        #pragma unroll
        for (int r = 1; r < 16; ++r) mx = fmaxf(mx, s0[r]);
        #pragma unroll
        for (int r = 0; r < 16; ++r) mx = fmaxf(mx, s1[r]);
        mx = fmaxf(mx, __shfl_xor(mx, 32));
        float mn = fmaxf(mrun, mx);
        float alpha = __expf(mrun - mn);
        mrun = mn;
        float rs = 0.f;
        #pragma unroll
        for (int r = 0; r < 16; ++r) {
            float p0 = __expf(s0[r] - mn);
            float p1 = __expf(s1[r] - mn);
            s0[r] = p0; s1[r] = p1;
            rs += p0 + p1;
        }
        rs += __shfl_xor(rs, 32);
        lrun = lrun * alpha + rs;
        #pragma unroll
        for (int r = 0; r < 16; ++r) { O0[r] *= alpha; O1[r] *= alpha; }

        // P^T -> LDS as [q][key]
        #pragma unroll
        for (int r = 0; r < 16; ++r) {
            int krel = (r & 3) + ((r >> 2) << 3) + 4 * laneK;
            Pl[laneM * 68 + krel]      = s0[r];
            Pl[laneM * 68 + 32 + krel] = s1[r];
        }
        __asm__ volatile("s_waitcnt lgkmcnt(0)" ::: "memory");
        __builtin_amdgcn_sched_barrier(0);

        // O^T += Vt P^T
        #pragma unroll
        for (int ks = 0; ks < 4; ++ks) {
            const float* pr = &Pl[laneM * 68 + 16 * ks + 8 * laneK];
            float4 pa = *(const float4*)pr;
            float4 pb = *(const float4*)(pr + 4);
            float pv[8] = {pa.x, pa.y, pa.z, pa.w, pb.x, pb.y, pb.z, pb.w};
            bhalf8 ph, plo;                     // RTZ split (P >= 0)
            #pragma unroll
            for (int i = 0; i < 8; ++i) {
                unsigned u = __float_as_uint(pv[i]);
                ph[i] = (short)(u >> 16);
                float lf = pv[i] - __uint_as_float(u & 0xFFFF0000u);
                plo[i] = (short)(__float_as_uint(lf) >> 16);
            }
            int db = 32 * ks + 16 * laneK;
            __builtin_amdgcn_s_setprio(1);
            {
                int col = laneM;
                int o = (col * 128 + db) ^ ((col & 7) << 4);
                bhalf8 vh = *(const bhalf8*)(lds + 16384 + o);
                bhalf8 vl = *(const bhalf8*)(lds + 24576 + o);
                O0 = __builtin_amdgcn_mfma_f32_32x32x16_bf16(vh, ph,  O0, 0, 0, 0);
                O0 = __builtin_amdgcn_mfma_f32_32x32x16_bf16(vl, ph,  O0, 0, 0, 0);
                O0 = __builtin_amdgcn_mfma_f32_32x32x16_bf16(vh, plo, O0, 0, 0, 0);
            }
            {
                int col = 32 + laneM;
                int o = (col * 128 + db) ^ ((col & 7) << 4);
                bhalf8 vh = *(const bhalf8*)(lds + 16384 + o);
                bhalf8 vl = *(const bhalf8*)(lds + 24576 + o);
                O1 = __builtin_amdgcn_mfma_f32_32x32x16_bf16(vh, ph,  O1, 0, 0, 0);
                O1 = __builtin_amdgcn_mfma_f32_32x32x16_bf16(vl, ph,  O1, 0, 0, 0);
                O1 = __builtin_amdgcn_mfma_f32_32x32x16_bf16(vh, plo, O1, 0, 0, 0);
            }
            __builtin_amdgcn_s_setprio(0);
        }
    }

    // Epilogue: transpose O^T through per-wave LDS, coalesced bf16-pair store
    float inv = 1.0f / lrun;
    #pragma unroll
    for (int r = 0; r < 16; ++r) {
        int d = (r & 3) + ((r >> 2) << 3) + 4 * laneK;
        Pl[laneM * 68 + d]      = O0[r] * inv;
        Pl[laneM * 68 + 32 + d] = O1[r] * inv;
    }
    __asm__ volatile("s_waitcnt lgkmcnt(0)" ::: "memory");
    __builtin_amdgcn_sched_barrier(0);
    #pragma unroll
    for (int it = 0; it < 16; ++it) {
        int qr = it * 2 + (lane >> 5);          // q-row within wave band
        int d  = (lane & 31) * 2;
        float2 v = *(const float2*)&Pl[qr * 68 + d];
        unsigned short h0, l0, h1, l1;
        split_bf16(v.x, h0, l0);
        split_bf16(v.y, h1, l1);
        size_t base = (size_t)(b * SS + q0 + 32 * wq + qr) * 512 + hh * 64 + d;
        ushort2 hv; hv.x = h0; hv.y = h1;
        ushort2 lv; lv.x = l0; lv.y = l1;
        *(ushort2*)(avh + base) = hv;
        *(ushort2*)(avl + base) = lv;
    }
}

// ---------------------------------------------------------------------------
// Fused residual-add + LayerNorm; also emits bf16 hi/lo pair of the output.
// ---------------------------------------------------------------------------
__global__ __launch_bounds__(256) void add_ln_kernel(
    float* __restrict__ h, const float* __restrict__ x,
    const float* __restrict__ g, const float* __restrict__ bta,
    unsigned short* __restrict__ hhi, unsigned short* __restrict__ hlo)
{
    int tok = blockIdx.x, tid = threadIdx.x;
    size_t base = (size_t)tok * DD;
    float v0 = h[base + tid] + x[base + tid];
    float v1 = h[base + 256 + tid] + x[base + 256 + tid];

    __shared__ float rs[256], rq[256];
    rs[tid] = v0 + v1;
    rq[tid] = v0 * v0 + v1 * v1;
    __syncthreads();
    for (int off = 128; off > 0; off >>= 1) {
        if (tid < off) { rs[tid] += rs[tid + off]; rq[tid] += rq[tid + off]; }
        __syncthreads();
    }
    float mean = rs[0] * (1.f / 512.f);
    float var  = rq[0] * (1.f / 512.f) - mean * mean;
    float inv  = rsqrtf(var + 1e-5f);
    float o0 = (v0 - mean) * inv * g[tid]       + bta[tid];
    float o1 = (v1 - mean) * inv * g[256 + tid] + bta[256 + tid];
    h[base + tid]       = o0;
    h[base + 256 + tid] = o1;
    unsigned short a, b;
    split_bf16(o0, a, b); hhi[base + tid]       = a; hlo[base + tid]       = b;
    split_bf16(o1, a, b); hhi[base + 256 + tid] = a; hlo[base + 256 + tid] = b;
}

// ---------------------------------------------------------------------------
extern "C" void kernel_launch(void* const* d_in, const int* in_sizes, int n_in,
                              void* d_out, int out_size, void* d_ws, size_t ws_size,
                              hipStream_t stream)
{
    const int*   data = (const int*)d_in[0];
    const float* we   = (const float*)d_in[1];   // word_emb [V, D]
    const float* pe   = (const float*)d_in[2];   // pos_emb
    const float* Wq   = (const float*)d_in[3];   // [L, 512, 512]
    const float* Wkv  = (const float*)d_in[4];   // [L, 1024, 512]
    const float* Wo   = (const float*)d_in[5];   // [L, 512, 512]
    const float* g1   = (const float*)d_in[6];
    const float* bl1  = (const float*)d_in[7];
    const float* W1   = (const float*)d_in[8];   // [L, 2048, 512]
    const float* b1   = (const float*)d_in[9];
    const float* W2   = (const float*)d_in[10];  // [L, 512, 2048]
    const float* b2   = (const float*)d_in[11];
    const float* g2   = (const float*)d_in[12];
    const float* bl2  = (const float*)d_in[13];
    const float* outb = (const float*)d_in[14];  // [V]
    float* out = (float*)d_out;

    typedef unsigned short us;
    // Workspace layout (~227 MB)
    float* h    = (float*)d_ws;                          // TT*512 f32
    us* qhp  = (us*)(h + (size_t)TT * 512);              // 8 x (TT*512 us) block
    us* qlp  = qhp  + (size_t)TT * 512;
    us* khp  = qlp  + (size_t)TT * 512;
    us* klp  = khp  + (size_t)TT * 512;
    us* vthp = klp  + (size_t)TT * 512;
    us* vtlp = vthp + (size_t)TT * 512;
    us* avh  = vtlp + (size_t)TT * 512;
    us* avl  = avh  + (size_t)TT * 512;
    float* tmp = (float*)(avl + (size_t)TT * 512);       // TT*512 f32
    us* hhi  = (us*)(tmp + (size_t)TT * 512);
    us* hlo  = hhi + (size_t)TT * 512;
    // ff pair aliases the q..av block (dead when ff is live): 2 x TT*2048 us
    us* ffh = qhp;
    us* ffl = qhp + (size_t)TT * 2048;
    // pre-converted weights (bf16 hi/lo)
    us* wqh  = hlo + (size_t)TT * 512;
    us* wql  = wqh  + (size_t)LL * 512 * 512;
    us* wkvh = wql  + (size_t)LL * 512 * 512;
    us* wkvl = wkvh + (size_t)LL * 1024 * 512;
    us* woh  = wkvl + (size_t)LL * 1024 * 512;
    us* wol  = woh  + (size_t)LL * 512 * 512;
    us* w1h  = wol  + (size_t)LL * 512 * 512;
    us* w1l  = w1h  + (size_t)LL * 2048 * 512;
    us* w2h  = w1l  + (size_t)LL * 2048 * 512;
    us* w2l  = w2h  + (size_t)LL * 512 * 2048;
    us* weh  = w2l  + (size_t)LL * 512 * 2048;
    us* wel  = weh  + (size_t)VV * 512;

    auto cv = [&](const float* s, us* hh, us* ll, size_t n) {
        int n4 = (int)(n >> 2);
        int blocks = (n4 + 255) / 256;
        if (blocks > 2048) blocks = 2048;
        convsplit<<<blocks, 256, 0, stream>>>(s, hh, ll, n4);
    };
    cv(Wq,  wqh,  wql,  (size_t)LL * 512 * 512);
    cv(Wkv, wkvh, wkvl, (size_t)LL * 1024 * 512);
    cv(Wo,  woh,  wol,  (size_t)LL * 512 * 512);
    cv(W1,  w1h,  w1l,  (size_t)LL * 2048 * 512);
    cv(W2,  w2h,  w2l,  (size_t)LL * 512 * 2048);
    cv(we,  weh,  wel,  (size_t)VV * 512);

    embed_kernel<<<TT, 256, 0, stream>>>(data, we, pe, h, hhi, hlo);

    for (int l = 0; l < LL; ++l) {
        const us* lwqh  = wqh  + (size_t)l * 512 * 512;
        const us* lwql  = wql  + (size_t)l * 512 * 512;
        const us* lwkvh = wkvh + (size_t)l * 1024 * 512;
        const us* lwkvl = wkvl + (size_t)l * 1024 * 512;
        const us* lwoh  = woh  + (size_t)l * 512 * 512;
        const us* lwol  = wol  + (size_t)l * 512 * 512;
        const us* lw1h  = w1h  + (size_t)l * 2048 * 512;
        const us* lw1l  = w1l  + (size_t)l * 2048 * 512;
        const us* lw2h  = w2h  + (size_t)l * 512 * 2048;
        const us* lw2l  = w2l  + (size_t)l * 512 * 2048;

        gemm_mfma<64, 3, false><<<dim3(8, 32), 256, 0, stream>>>(
            hhi, hlo, lwqh, lwql, nullptr, nullptr, qhp, qlp, nullptr, nullptr, 512, 512);
        gemm_mfma<128, 4, false><<<dim3(8, 32), 256, 0, stream>>>(
            hhi, hlo, lwkvh, lwkvl, nullptr, nullptr, khp, klp, vthp, vtlp, 1024, 512);
        flash_mfma<<<dim3(16, HH, BB), 128, 0, stream>>>(
            qhp, qlp, khp, klp, vthp, vtlp, avh, avl);
        gemm_mfma<64, 0, false><<<dim3(8, 32), 256, 0, stream>>>(
            avh, avl, lwoh, lwol, nullptr, tmp, nullptr, nullptr, nullptr, nullptr, 512, 512);
        add_ln_kernel<<<TT, 256, 0, stream>>>(h, tmp, g1 + l * 512, bl1 + l * 512, hhi, hlo);
        gemm_mfma<128, 2, false><<<dim3(16, 32), 256, 0, stream>>>(
            hhi, hlo, lw1h, lw1l, b1 + l * 2048, nullptr, ffh, ffl, nullptr, nullptr, 2048, 512);
        gemm_mfma<64, 1, false><<<dim3(8, 32), 256, 0, stream>>>(
            ffh, ffl, lw2h, lw2l, b2 + l * 512, tmp, nullptr, nullptr, nullptr, nullptr, 512, 2048);
        add_ln_kernel<<<TT, 256, 0, stream>>>(h, tmp, g2 + l * 512, bl2 + l * 512, hhi, hlo);
    }

    // logits = h @ word_emb^T + out_b (tied), N = 10000, serpentine XCD swizzle
    gemm_mfma<128, 1, true><<<dim3((VV + 127) / 128, 32), 256, 0, stream>>>(
        hhi, hlo, weh, wel, outb, out, nullptr, nullptr, nullptr, nullptr, VV, 512);
}

// Round 4
// 3217.861 us; speedup vs baseline: 1.5815x; 1.5815x over previous
//
#include <hip/hip_runtime.h>

// Problem constants
#define VV 10000
#define DD 512
#define HH 8
#define DH 64
#define DI 2048
#define LL 12
#define BB 4
#define SS 1024
#define TT (BB * SS)   // 4096 tokens

// All GEMMs and attention on matrix cores via split-bf16:
// x = hi + lo (both bf16), A*B ~= Ah*Bh + Ah*Bl + Al*Bh, fp32 MFMA accum.
// Round 4: register staging (round-3 lesson: global_load_lds with a
// scattered per-wave source = 64 cache lines per instr = 2x slower;
// slot-major LDS layouts must reg-stage). K-loop restructured as
// async-STAGE split: next tile's loads issue BEFORE the MFMA cluster.
// Serpentine XCD swizzle kept for logits (proven FETCH 329->126 MB).

typedef __attribute__((ext_vector_type(8))) short bhalf8;    // 8 bf16 = 4 VGPRs
typedef __attribute__((ext_vector_type(16))) float f32x16;   // MFMA 32x32 accum

// RNE split of fp32 into bf16 hi + bf16 lo.
__device__ __forceinline__ void split_bf16(float x, unsigned short& h, unsigned short& l)
{
    unsigned int u = __float_as_uint(x);
    unsigned int r = (u + 0x7FFFu + ((u >> 16) & 1u)) & 0xFFFF0000u;
    h = (unsigned short)(r >> 16);
    float lf = x - __uint_as_float(r);          // exact (Sterbenz-range)
    unsigned int ul = __float_as_uint(lf);
    l = (unsigned short)((ul + 0x7FFFu + ((ul >> 16) & 1u)) >> 16);
}

// ---------------------------------------------------------------------------
// fp32 -> (bf16 hi, bf16 lo) bulk converter. n4 = element count / 4.
// ---------------------------------------------------------------------------
__global__ __launch_bounds__(256) void convsplit(
    const float* __restrict__ src, unsigned short* __restrict__ hi,
    unsigned short* __restrict__ lo, int n4)
{
    int stride = gridDim.x * 256;
    for (int i = blockIdx.x * 256 + threadIdx.x; i < n4; i += stride) {
        float4 v = ((const float4*)src)[i];
        ushort4 h, l;
        split_bf16(v.x, h.x, l.x);
        split_bf16(v.y, h.y, l.y);
        split_bf16(v.z, h.z, l.z);
        split_bf16(v.w, h.w, l.w);
        ((ushort4*)hi)[i] = h;
        ((ushort4*)lo)[i] = l;
    }
}

// ---------------------------------------------------------------------------
// Embedding: h = word_emb[data] + pos_emb ; also emits bf16 hi/lo pair.
// ---------------------------------------------------------------------------
__global__ __launch_bounds__(256) void embed_kernel(
    const int* __restrict__ data, const float* __restrict__ we,
    const float* __restrict__ pe, float* __restrict__ h,
    unsigned short* __restrict__ hhi, unsigned short* __restrict__ hlo)
{
    int tok = blockIdx.x;
    int tid = threadIdx.x;
    int idx = data[tok];
    int s = tok & (SS - 1);
    size_t base = (size_t)tok * DD;
    size_t wb = (size_t)idx * DD;
    size_t pb = (size_t)s * DD;
    float a = we[wb + tid] + pe[pb + tid];
    float b = we[wb + 256 + tid] + pe[pb + 256 + tid];
    h[base + tid] = a;
    h[base + 256 + tid] = b;
    unsigned short hx, lx;
    split_bf16(a, hx, lx); hhi[base + tid] = hx;       hlo[base + tid] = lx;
    split_bf16(b, hx, lx); hhi[base + 256 + tid] = hx; hlo[base + 256 + tid] = lx;
}

// ---------------------------------------------------------------------------
// Split-bf16 MFMA GEMM: C[M,N] = A[M,K] * W[N,K]^T (+bias)(+relu)
// Block tile 128 x BN, 4 waves (2x2), wave tile 64 x BN/2,
// fragments 32x32 via v_mfma_f32_32x32x16_bf16 (3 MFMA per fragment pair).
// LDS: A-hi 16K | A-lo 16K | B-hi BT | B-lo BT; within each buffer:
// byte = slot*(rows*16) + ((row^slot)<<4)  (slot-major, XOR swizzle;
// measured 0 bank conflicts on both ds_write_b128 and ds_read_b128).
// Staging: REGISTER staged (see round-3 lesson at top), K-loop is an
// async-STAGE split: loads for tile k+1 issue before tile k's MFMAs.
// All staged buffers live in one workspace; addresses are int element
// offsets from Ahp (precomputed, k-invariant).
// EPI: 0 fp32, 1 fp32+bias, 2 bias+relu->pair, 3 pair,
//      4 kv: n<512 -> K pair [m][512]; n>=512 -> Vt pair [(n-512)*TT + m].
// SWZ: serpentine n-chunk XCD remap - ONLY valid for grid (79,32) (logits).
// ---------------------------------------------------------------------------
template<int BN, int EPI, bool SWZ>
__global__ __launch_bounds__(256) void gemm_mfma(
    const unsigned short* __restrict__ Ahp, const unsigned short* __restrict__ Alp,
    const unsigned short* __restrict__ Whp, const unsigned short* __restrict__ Wlp,
    const float* __restrict__ bias, float* __restrict__ C,
    unsigned short* __restrict__ Chp, unsigned short* __restrict__ Clp,
    unsigned short* __restrict__ Vhp, unsigned short* __restrict__ Vlp,
    int N, int K)
{
    constexpr int FN  = BN / 64;           // n-fragments per wave
    constexpr int BT  = BN * 128;          // bytes per B tile (8 slots * BN * 16)
    constexpr int NBG = BN / 8;            // 8-row staging groups per B tile
    constexpr int NGRP = 32 + 2 * NBG;     // total staging groups per K-step
    constexpr int PW  = NGRP / 4;          // groups per wave
    __shared__ __align__(16) char smem[32768 + 2 * BT];  // Ah|Al|Bh|Bl

    int bx = blockIdx.x, by = blockIdx.y;
    if (SWZ) {
        // grid = (79, 32). XCD residue class x gets t in [x*316, x*316+316):
        // serpentine order = for n-chunk (7x10 + 1x9 panels): for band in 32:
        // for panel in chunk. W chunk (~2.6 MB pair) stays L2-resident per XCD.
        int id = by * 79 + bx;
        int t  = (id & 7) * 316 + (id >> 3);
        if (t < 2240) { int c = t / 320, r = t - c * 320; by = r / 10; bx = c * 10 + r % 10; }
        else          { int r = t - 2240;                 by = r / 9;  bx = 70 + r % 9; }
    }

    const int tid   = threadIdx.x;
    const int lane  = tid & 63;
    const int wid   = tid >> 6;
    const int wm    = wid >> 1;
    const int wn    = wid & 1;
    const int laneM = lane & 31;
    const int laneK = lane >> 5;
    const int m0    = by * 128;
    const int n0    = bx * BN;
    const int srow8 = lane >> 3;           // row-within-group for staging
    const int sslot = lane & 7;            // k-chunk (8 bf16) for staging

    // Precomputed k-invariant staging addresses: element offsets from Ahp.
    // (Workspace is one allocation; activations precede weights, so all
    //  offsets are positive and < 2^27 elements.)
    const int dAl = (int)(Alp - Ahp);
    const int dW  = (int)(Whp - Ahp);
    const int dWl = (int)(Wlp - Ahp);
    int offs[PW];
    int ldso[PW];
    #pragma unroll
    for (int t = 0; t < PW; ++t) {
        int g = wid * PW + t;
        if (g < 32) {                      // A: groups 0-15 hi, 16-31 lo
            int row = (g & 15) * 8 + srow8;
            offs[t] = (g < 16 ? 0 : dAl) + (m0 + row) * K + sslot * 8;
            ldso[t] = ((g >> 4) << 14) + sslot * 2048 + ((row ^ sslot) << 4);
        } else {                           // B: NBG groups hi, NBG lo
            int d = g - 32;
            int row = (d & (NBG - 1)) * 8 + srow8;
            int n = n0 + row;
            n = (n < N) ? n : (N - 1);     // clamp (logits tail); stores guarded
            offs[t] = (d < NBG ? dW : dWl) + n * K + sslot * 8;
            ldso[t] = 32768 + ((d < NBG) ? 0 : BT)
                    + sslot * (BN * 16) + ((row ^ sslot) << 4);
        }
    }

    f32x16 acc[2][FN];
    #pragma unroll
    for (int i = 0; i < 2; ++i)
        #pragma unroll
        for (int j = 0; j < FN; ++j)
            #pragma unroll
            for (int r = 0; r < 16; ++r) acc[i][j][r] = 0.f;

    bhalf8 rbuf[PW];
    #pragma unroll
    for (int t = 0; t < PW; ++t)           // prologue: tile 0 loads
        rbuf[t] = *(const bhalf8*)(Ahp + offs[t]);

    for (int k0 = 0; k0 < K; k0 += 64) {
        __syncthreads();                   // previous tile's LDS reads done
        #pragma unroll
        for (int t = 0; t < PW; ++t)
            *(bhalf8*)(smem + ldso[t]) = rbuf[t];
        __syncthreads();                   // staging visible

        if (k0 + 64 < K) {                 // issue NEXT tile's loads now;
            #pragma unroll                 // latency hides under the MFMAs
            for (int t = 0; t < PW; ++t)
                rbuf[t] = *(const bhalf8*)(Ahp + offs[t] + k0 + 64);
        }

        #pragma unroll
        for (int kb = 0; kb < 4; ++kb) {   // 4 x (k=16) per K-step
            const int slot = kb * 2 + laneK;
            bhalf8 ah[2], al[2], bh[FN], bl[FN];
            #pragma unroll
            for (int i = 0; i < 2; ++i) {
                int row = wm * 64 + i * 32 + laneM;
                int off = slot * 2048 + ((row ^ slot) << 4);
                ah[i] = *(const bhalf8*)(smem + off);
                al[i] = *(const bhalf8*)(smem + 16384 + off);
            }
            #pragma unroll
            for (int j = 0; j < FN; ++j) {
                int row = wn * (BN / 2) + j * 32 + laneM;
                int off = 32768 + slot * (BN * 16) + ((row ^ slot) << 4);
                bh[j] = *(const bhalf8*)(smem + off);
                bl[j] = *(const bhalf8*)(smem + BT + off);
            }
            #pragma unroll
            for (int i = 0; i < 2; ++i)
                #pragma unroll
                for (int j = 0; j < FN; ++j) {
                    acc[i][j] = __builtin_amdgcn_mfma_f32_32x32x16_bf16(ah[i], bh[j], acc[i][j], 0, 0, 0);
                    acc[i][j] = __builtin_amdgcn_mfma_f32_32x32x16_bf16(ah[i], bl[j], acc[i][j], 0, 0, 0);
                    acc[i][j] = __builtin_amdgcn_mfma_f32_32x32x16_bf16(al[i], bh[j], acc[i][j], 0, 0, 0);
                }
        }
    }

    // Epilogue. C/D layout: col = lane&31, row = (r&3)+8*(r>>2)+4*laneK
    #pragma unroll
    for (int j = 0; j < FN; ++j) {
        int ncol = n0 + wn * (BN / 2) + j * 32 + laneM;
        bool nok = (ncol < N);
        float bv = 0.f;
        if (EPI == 1 || EPI == 2) { if (nok) bv = bias[ncol]; }
        #pragma unroll
        for (int i = 0; i < 2; ++i) {
            #pragma unroll
            for (int r = 0; r < 16; ++r) {
                int mrow = m0 + wm * 64 + i * 32 + (r & 3) + ((r >> 2) << 3) + laneK * 4;
                float v = acc[i][j][r] + bv;
                if (EPI == 2) v = fmaxf(v, 0.f);
                if (nok) {
                    if (EPI == 2 || EPI == 3) {
                        unsigned short hx, lx;
                        split_bf16(v, hx, lx);
                        Chp[(size_t)mrow * N + ncol] = hx;
                        Clp[(size_t)mrow * N + ncol] = lx;
                    } else if (EPI == 4) {
                        unsigned short hx, lx;
                        split_bf16(v, hx, lx);
                        if (ncol < 512) {
                            Chp[(size_t)mrow * 512 + ncol] = hx;
                            Clp[(size_t)mrow * 512 + ncol] = lx;
                        } else {
                            Vhp[(size_t)(ncol - 512) * TT + mrow] = hx;
                            Vlp[(size_t)(ncol - 512) * TT + mrow] = lx;
                        }
                    } else {
                        C[(size_t)mrow * N + ncol] = v;
                    }
                }
            }
        }
    }
}

// ---------------------------------------------------------------------------
// MFMA flash attention (split-bf16, causal). One block = 64 q-rows x (head,b),
// 128 threads = 2 waves; wave wq owns q-rows [32*wq, 32*wq+32).
// Swapped QK^T: s = mfma(K, Q) -> C[key][q], col = q = lane&31 -> each lane
// holds 32 keys of ONE q-row; softmax stats are per-lane scalars + one
// shfl_xor(32). P transposed via per-wave LDS, RTZ-split, PV = mfma(Vt, P).
// LDS: K hi/lo + Vt hi/lo (XOR-swizzled, conflict-free b128) + P per wave.
// Register-staged (round-3 lesson). setprio(1) around MFMA clusters.
// ---------------------------------------------------------------------------
__global__ __launch_bounds__(128) void flash_mfma(
    const unsigned short* __restrict__ qhp, const unsigned short* __restrict__ qlp,
    const unsigned short* __restrict__ khp, const unsigned short* __restrict__ klp,
    const unsigned short* __restrict__ vthp, const unsigned short* __restrict__ vtlp,
    unsigned short* __restrict__ avh, unsigned short* __restrict__ avl)
{
    __shared__ __align__(16) char lds[50176];   // K 16K | Vt 16K | P 2x8704

    const int qt  = 15 - (int)blockIdx.x;       // heavy q-tiles first
    const int hh  = blockIdx.y;
    const int b   = blockIdx.z;
    const int tid = threadIdx.x;
    const int lane  = tid & 63;
    const int wq    = tid >> 6;
    const int laneM = lane & 31;
    const int laneK = lane >> 5;
    const int q0    = qt * 64;

    // Q fragments (B-operand): col q = laneM, k(d) = 16*ks + 8*laneK + i
    bhalf8 Qh[4], Ql[4];
    {
        size_t qoff = (size_t)(b * SS + q0 + 32 * wq + laneM) * 512 + hh * 64 + 8 * laneK;
        #pragma unroll
        for (int ks = 0; ks < 4; ++ks) {
            Qh[ks] = *(const bhalf8*)(qhp + qoff + 16 * ks);
            Ql[ks] = *(const bhalf8*)(qlp + qoff + 16 * ks);
        }
    }

    f32x16 O0, O1;                              // O^T frags: d-blocks 0,1
    #pragma unroll
    for (int r = 0; r < 16; ++r) { O0[r] = 0.f; O1[r] = 0.f; }
    float mrun = -1e30f, lrun = 0.f;            // per-lane (q = laneM)

    const int srow  = tid >> 1;                 // 0..63 staging row
    const int shalf = tid & 1;                  // 32-elem half
    float* Pl = (float*)(lds + 32768 + wq * 8704);   // [32 q][68]

    for (int kt = 0; kt <= qt; ++kt) {
        __syncthreads();                        // prev-tile LDS reads done
        {
            size_t kbase = (size_t)(b * SS + kt * 64 + srow) * 512 + hh * 64 + 32 * shalf;
            size_t vbase = (size_t)(hh * 64 + srow) * TT + b * SS + kt * 64 + 32 * shalf;
            bhalf8 k0[4], k1[4], v0[4], v1[4];
            #pragma unroll
            for (int j = 0; j < 4; ++j) {
                k0[j] = *(const bhalf8*)(khp  + kbase + 8 * j);
                k1[j] = *(const bhalf8*)(klp  + kbase + 8 * j);
                v0[j] = *(const bhalf8*)(vthp + vbase + 8 * j);
                v1[j] = *(const bhalf8*)(vtlp + vbase + 8 * j);
            }
            int ob = srow * 128 + 64 * shalf;
            int sw = (srow & 7) << 4;
            #pragma unroll
            for (int j = 0; j < 4; ++j) {
                int o = (ob + 16 * j) ^ sw;
                *(bhalf8*)(lds + o)         = k0[j];
                *(bhalf8*)(lds + 8192 + o)  = k1[j];
                *(bhalf8*)(lds + 16384 + o) = v0[j];
                *(bhalf8*)(lds + 24576 + o) = v1[j];
            }
        }
        __syncthreads();                        // tiles staged

        // S^T = K Q^T  (frag s0: keys 0-31, s1: keys 32-63; col = q)
        f32x16 s0, s1;
        #pragma unroll
        for (int r = 0; r < 16; ++r) { s0[r] = 0.f; s1[r] = 0.f; }
        __builtin_amdgcn_s_setprio(1);
        #pragma unroll
        for (int ks = 0; ks < 4; ++ks) {
            int db = 32 * ks + 16 * laneK;
            int o0 = (laneM * 128 + db) ^ ((laneM & 7) << 4);
            int r1 = 32 + laneM;
            int o1 = (r1 * 128 + db) ^ ((r1 & 7) << 4);
            bhalf8 kh0 = *(const bhalf8*)(lds + o0);
            bhalf8 kl0 = *(const bhalf8*)(lds + 8192 + o0);
            bhalf8 kh1 = *(const bhalf8*)(lds + o1);
            bhalf8 kl1 = *(const bhalf8*)(lds + 8192 + o1);
            s0 = __builtin_amdgcn_mfma_f32_32x32x16_bf16(kh0, Qh[ks], s0, 0, 0, 0);
            s0 = __builtin_amdgcn_mfma_f32_32x32x16_bf16(kh0, Ql[ks], s0, 0, 0, 0);
            s0 = __builtin_amdgcn_mfma_f32_32x32x16_bf16(kl0, Qh[ks], s0, 0, 0, 0);
            s1 = __builtin_amdgcn_mfma_f32_32x32x16_bf16(kh1, Qh[ks], s1, 0, 0, 0);
            s1 = __builtin_amdgcn_mfma_f32_32x32x16_bf16(kh1, Ql[ks], s1, 0, 0, 0);
            s1 = __builtin_amdgcn_mfma_f32_32x32x16_bf16(kl1, Qh[ks], s1, 0, 0, 0);
        }
        __builtin_amdgcn_s_setprio(0);

        #pragma unroll
        for (int r = 0; r < 16; ++r) { s0[r] *= 0.125f; s1[r] *= 0.125f; }

        if (kt == qt) {                         // causal mask on diagonal tile
            int qrel = 32 * wq + laneM;
            #pragma unroll
            for (int r = 0; r < 16; ++r) {
                int krel = (r & 3) + ((r >> 2) << 3) + 4 * laneK;
                if (krel > qrel)      s0[r] = -1e30f;
                if (krel + 32 > qrel) s1[r] = -1e30f;
            }
        }

        // online softmax, per-lane scalars (lane = one q-row, 32 of 64 keys;
        // partner lane^32 holds the other 32)
        float mx = s0[0];
        #pragma unroll
        for (int r = 1; r < 16; ++r) mx = fmaxf(mx, s0[r]);
        #pragma unroll
        for (int r = 0; r < 16; ++r) mx = fmaxf(mx, s1[r]);
        mx = fmaxf(mx, __shfl_xor(mx, 32));
        float mn = fmaxf(mrun, mx);
        float alpha = __expf(mrun - mn);
        mrun = mn;
        float rs = 0.f;
        #pragma unroll
        for (int r = 0; r < 16; ++r) {
            float p0 = __expf(s0[r] - mn);
            float p1 = __expf(s1[r] - mn);
            s0[r] = p0; s1[r] = p1;
            rs += p0 + p1;
        }
        rs += __shfl_xor(rs, 32);
        lrun = lrun * alpha + rs;
        #pragma unroll
        for (int r = 0; r < 16; ++r) { O0[r] *= alpha; O1[r] *= alpha; }

        // P^T -> LDS as [q][key]
        #pragma unroll
        for (int r = 0; r < 16; ++r) {
            int krel = (r & 3) + ((r >> 2) << 3) + 4 * laneK;
            Pl[laneM * 68 + krel]      = s0[r];
            Pl[laneM * 68 + 32 + krel] = s1[r];
        }
        __asm__ volatile("s_waitcnt lgkmcnt(0)" ::: "memory");
        __builtin_amdgcn_sched_barrier(0);

        // O^T += Vt P^T
        #pragma unroll
        for (int ks = 0; ks < 4; ++ks) {
            const float* pr = &Pl[laneM * 68 + 16 * ks + 8 * laneK];
            float4 pa = *(const float4*)pr;
            float4 pb = *(const float4*)(pr + 4);
            float pv[8] = {pa.x, pa.y, pa.z, pa.w, pb.x, pb.y, pb.z, pb.w};
            bhalf8 ph, plo;                     // RTZ split (P >= 0)
            #pragma unroll
            for (int i = 0; i < 8; ++i) {
                unsigned u = __float_as_uint(pv[i]);
                ph[i] = (short)(u >> 16);
                float lf = pv[i] - __uint_as_float(u & 0xFFFF0000u);
                plo[i] = (short)(__float_as_uint(lf) >> 16);
            }
            int db = 32 * ks + 16 * laneK;
            __builtin_amdgcn_s_setprio(1);
            {
                int col = laneM;
                int o = (col * 128 + db) ^ ((col & 7) << 4);
                bhalf8 vh = *(const bhalf8*)(lds + 16384 + o);
                bhalf8 vl = *(const bhalf8*)(lds + 24576 + o);
                O0 = __builtin_amdgcn_mfma_f32_32x32x16_bf16(vh, ph,  O0, 0, 0, 0);
                O0 = __builtin_amdgcn_mfma_f32_32x32x16_bf16(vl, ph,  O0, 0, 0, 0);
                O0 = __builtin_amdgcn_mfma_f32_32x32x16_bf16(vh, plo, O0, 0, 0, 0);
            }
            {
                int col = 32 + laneM;
                int o = (col * 128 + db) ^ ((col & 7) << 4);
                bhalf8 vh = *(const bhalf8*)(lds + 16384 + o);
                bhalf8 vl = *(const bhalf8*)(lds + 24576 + o);
                O1 = __builtin_amdgcn_mfma_f32_32x32x16_bf16(vh, ph,  O1, 0, 0, 0);
                O1 = __builtin_amdgcn_mfma_f32_32x32x16_bf16(vl, ph,  O1, 0, 0, 0);
                O1 = __builtin_amdgcn_mfma_f32_32x32x16_bf16(vh, plo, O1, 0, 0, 0);
            }
            __builtin_amdgcn_s_setprio(0);
        }
    }

    // Epilogue: transpose O^T through per-wave LDS, coalesced bf16-pair store
    float inv = 1.0f / lrun;
    #pragma unroll
    for (int r = 0; r < 16; ++r) {
        int d = (r & 3) + ((r >> 2) << 3) + 4 * laneK;
        Pl[laneM * 68 + d]      = O0[r] * inv;
        Pl[laneM * 68 + 32 + d] = O1[r] * inv;
    }
    __asm__ volatile("s_waitcnt lgkmcnt(0)" ::: "memory");
    __builtin_amdgcn_sched_barrier(0);
    #pragma unroll
    for (int it = 0; it < 16; ++it) {
        int qr = it * 2 + (lane >> 5);          // q-row within wave band
        int d  = (lane & 31) * 2;
        float2 v = *(const float2*)&Pl[qr * 68 + d];
        unsigned short h0, l0, h1, l1;
        split_bf16(v.x, h0, l0);
        split_bf16(v.y, h1, l1);
        size_t base = (size_t)(b * SS + q0 + 32 * wq + qr) * 512 + hh * 64 + d;
        ushort2 hv; hv.x = h0; hv.y = h1;
        ushort2 lv; lv.x = l0; lv.y = l1;
        *(ushort2*)(avh + base) = hv;
        *(ushort2*)(avl + base) = lv;
    }
}

// ---------------------------------------------------------------------------
// Fused residual-add + LayerNorm; also emits bf16 hi/lo pair of the output.
// ---------------------------------------------------------------------------
__global__ __launch_bounds__(256) void add_ln_kernel(
    float* __restrict__ h, const float* __restrict__ x,
    const float* __restrict__ g, const float* __restrict__ bta,
    unsigned short* __restrict__ hhi, unsigned short* __restrict__ hlo)
{
    int tok = blockIdx.x, tid = threadIdx.x;
    size_t base = (size_t)tok * DD;
    float v0 = h[base + tid] + x[base + tid];
    float v1 = h[base + 256 + tid] + x[base + 256 + tid];

    __shared__ float rs[256], rq[256];
    rs[tid] = v0 + v1;
    rq[tid] = v0 * v0 + v1 * v1;
    __syncthreads();
    for (int off = 128; off > 0; off >>= 1) {
        if (tid < off) { rs[tid] += rs[tid + off]; rq[tid] += rq[tid + off]; }
        __syncthreads();
    }
    float mean = rs[0] * (1.f / 512.f);
    float var  = rq[0] * (1.f / 512.f) - mean * mean;
    float inv  = rsqrtf(var + 1e-5f);
    float o0 = (v0 - mean) * inv * g[tid]       + bta[tid];
    float o1 = (v1 - mean) * inv * g[256 + tid] + bta[256 + tid];
    h[base + tid]       = o0;
    h[base + 256 + tid] = o1;
    unsigned short a, b;
    split_bf16(o0, a, b); hhi[base + tid]       = a; hlo[base + tid]       = b;
    split_bf16(o1, a, b); hhi[base + 256 + tid] = a; hlo[base + 256 + tid] = b;
}

// ---------------------------------------------------------------------------
extern "C" void kernel_launch(void* const* d_in, const int* in_sizes, int n_in,
                              void* d_out, int out_size, void* d_ws, size_t ws_size,
                              hipStream_t stream)
{
    const int*   data = (const int*)d_in[0];
    const float* we   = (const float*)d_in[1];   // word_emb [V, D]
    const float* pe   = (const float*)d_in[2];   // pos_emb
    const float* Wq   = (const float*)d_in[3];   // [L, 512, 512]
    const float* Wkv  = (const float*)d_in[4];   // [L, 1024, 512]
    const float* Wo   = (const float*)d_in[5];   // [L, 512, 512]
    const float* g1   = (const float*)d_in[6];
    const float* bl1  = (const float*)d_in[7];
    const float* W1   = (const float*)d_in[8];   // [L, 2048, 512]
    const float* b1   = (const float*)d_in[9];
    const float* W2   = (const float*)d_in[10];  // [L, 512, 2048]
    const float* b2   = (const float*)d_in[11];
    const float* g2   = (const float*)d_in[12];
    const float* bl2  = (const float*)d_in[13];
    const float* outb = (const float*)d_in[14];  // [V]
    float* out = (float*)d_out;

    typedef unsigned short us;
    // Workspace layout (~227 MB). Activations FIRST, weights AFTER
    // (gemm staging uses positive int offsets from its A pointer).
    float* h    = (float*)d_ws;                          // TT*512 f32
    us* qhp  = (us*)(h + (size_t)TT * 512);              // 8 x (TT*512 us) block
    us* qlp  = qhp  + (size_t)TT * 512;
    us* khp  = qlp  + (size_t)TT * 512;
    us* klp  = khp  + (size_t)TT * 512;
    us* vthp = klp  + (size_t)TT * 512;
    us* vtlp = vthp + (size_t)TT * 512;
    us* avh  = vtlp + (size_t)TT * 512;
    us* avl  = avh  + (size_t)TT * 512;
    float* tmp = (float*)(avl + (size_t)TT * 512);       // TT*512 f32
    us* hhi  = (us*)(tmp + (size_t)TT * 512);
    us* hlo  = hhi + (size_t)TT * 512;
    // ff pair aliases the q..av block (dead when ff is live): 2 x TT*2048 us
    us* ffh = qhp;
    us* ffl = qhp + (size_t)TT * 2048;
    // pre-converted weights (bf16 hi/lo)
    us* wqh  = hlo + (size_t)TT * 512;
    us* wql  = wqh  + (size_t)LL * 512 * 512;
    us* wkvh = wql  + (size_t)LL * 512 * 512;
    us* wkvl = wkvh + (size_t)LL * 1024 * 512;
    us* woh  = wkvl + (size_t)LL * 1024 * 512;
    us* wol  = woh  + (size_t)LL * 512 * 512;
    us* w1h  = wol  + (size_t)LL * 512 * 512;
    us* w1l  = w1h  + (size_t)LL * 2048 * 512;
    us* w2h  = w1l  + (size_t)LL * 2048 * 512;
    us* w2l  = w2h  + (size_t)LL * 512 * 2048;
    us* weh  = w2l  + (size_t)LL * 512 * 2048;
    us* wel  = weh  + (size_t)VV * 512;

    auto cv = [&](const float* s, us* hh, us* ll, size_t n) {
        int n4 = (int)(n >> 2);
        int blocks = (n4 + 255) / 256;
        if (blocks > 2048) blocks = 2048;
        convsplit<<<blocks, 256, 0, stream>>>(s, hh, ll, n4);
    };
    cv(Wq,  wqh,  wql,  (size_t)LL * 512 * 512);
    cv(Wkv, wkvh, wkvl, (size_t)LL * 1024 * 512);
    cv(Wo,  woh,  wol,  (size_t)LL * 512 * 512);
    cv(W1,  w1h,  w1l,  (size_t)LL * 2048 * 512);
    cv(W2,  w2h,  w2l,  (size_t)LL * 512 * 2048);
    cv(we,  weh,  wel,  (size_t)VV * 512);

    embed_kernel<<<TT, 256, 0, stream>>>(data, we, pe, h, hhi, hlo);

    for (int l = 0; l < LL; ++l) {
        const us* lwqh  = wqh  + (size_t)l * 512 * 512;
        const us* lwql  = wql  + (size_t)l * 512 * 512;
        const us* lwkvh = wkvh + (size_t)l * 1024 * 512;
        const us* lwkvl = wkvl + (size_t)l * 1024 * 512;
        const us* lwoh  = woh  + (size_t)l * 512 * 512;
        const us* lwol  = wol  + (size_t)l * 512 * 512;
        const us* lw1h  = w1h  + (size_t)l * 2048 * 512;
        const us* lw1l  = w1l  + (size_t)l * 2048 * 512;
        const us* lw2h  = w2h  + (size_t)l * 512 * 2048;
        const us* lw2l  = w2l  + (size_t)l * 512 * 2048;

        gemm_mfma<64, 3, false><<<dim3(8, 32), 256, 0, stream>>>(
            hhi, hlo, lwqh, lwql, nullptr, nullptr, qhp, qlp, nullptr, nullptr, 512, 512);
        gemm_mfma<128, 4, false><<<dim3(8, 32), 256, 0, stream>>>(
            hhi, hlo, lwkvh, lwkvl, nullptr, nullptr, khp, klp, vthp, vtlp, 1024, 512);
        flash_mfma<<<dim3(16, HH, BB), 128, 0, stream>>>(
            qhp, qlp, khp, klp, vthp, vtlp, avh, avl);
        gemm_mfma<64, 0, false><<<dim3(8, 32), 256, 0, stream>>>(
            avh, avl, lwoh, lwol, nullptr, tmp, nullptr, nullptr, nullptr, nullptr, 512, 512);
        add_ln_kernel<<<TT, 256, 0, stream>>>(h, tmp, g1 + l * 512, bl1 + l * 512, hhi, hlo);
        gemm_mfma<128, 2, false><<<dim3(16, 32), 256, 0, stream>>>(
            hhi, hlo, lw1h, lw1l, b1 + l * 2048, nullptr, ffh, ffl, nullptr, nullptr, 2048, 512);
        gemm_mfma<64, 1, false><<<dim3(8, 32), 256, 0, stream>>>(
            ffh, ffl, lw2h, lw2l, b2 + l * 512, tmp, nullptr, nullptr, nullptr, nullptr, 512, 2048);
        add_ln_kernel<<<TT, 256, 0, stream>>>(h, tmp, g2 + l * 512, bl2 + l * 512, hhi, hlo);
    }

    // logits = h @ word_emb^T + out_b (tied), N = 10000, serpentine XCD swizzle
    gemm_mfma<128, 1, true><<<dim3((VV + 127) / 128, 32), 256, 0, stream>>>(
        hhi, hlo, weh, wel, outb, out, nullptr, nullptr, nullptr, nullptr, VV, 512);
}

// Round 5
// 2899.905 us; speedup vs baseline: 1.7548x; 1.1096x over previous
//
#include <hip/hip_runtime.h>

// Problem constants
#define VV 10000
#define DD 512
#define HH 8
#define DH 64
#define DI 2048
#define LL 12
#define BB 4
#define SS 1024
#define TT (BB * SS)   // 4096 tokens

// All GEMMs and attention on matrix cores via split-bf16:
// x = hi + lo (both bf16), A*B ~= Ah*Bh + Ah*Bl + Al*Bh, fp32 MFMA accum.
// Round 5: fused QKV GEMM (N=1536, BN=64, 768 blocks = 3/CU resident),
// 2-deep register prefetch for the 1-block/CU GEMMs (o-proj, ff2),
// q pre-scaled by 0.125 in the QKV epilogue (exact pow2, flash drops it).
// Round-4 lessons kept: reg staging (gload_lds scatters = 2x slower),
// async-STAGE prefetch, serpentine XCD swizzle on logits.

typedef __attribute__((ext_vector_type(8))) short bhalf8;    // 8 bf16 = 4 VGPRs
typedef __attribute__((ext_vector_type(16))) float f32x16;   // MFMA 32x32 accum

// RNE split of fp32 into bf16 hi + bf16 lo.
__device__ __forceinline__ void split_bf16(float x, unsigned short& h, unsigned short& l)
{
    unsigned int u = __float_as_uint(x);
    unsigned int r = (u + 0x7FFFu + ((u >> 16) & 1u)) & 0xFFFF0000u;
    h = (unsigned short)(r >> 16);
    float lf = x - __uint_as_float(r);          // exact (Sterbenz-range)
    unsigned int ul = __float_as_uint(lf);
    l = (unsigned short)((ul + 0x7FFFu + ((ul >> 16) & 1u)) >> 16);
}

// ---------------------------------------------------------------------------
// fp32 -> (bf16 hi, bf16 lo) bulk converter. n4 = element count / 4.
// ---------------------------------------------------------------------------
__global__ __launch_bounds__(256) void convsplit(
    const float* __restrict__ src, unsigned short* __restrict__ hi,
    unsigned short* __restrict__ lo, int n4)
{
    int stride = gridDim.x * 256;
    for (int i = blockIdx.x * 256 + threadIdx.x; i < n4; i += stride) {
        float4 v = ((const float4*)src)[i];
        ushort4 h, l;
        split_bf16(v.x, h.x, l.x);
        split_bf16(v.y, h.y, l.y);
        split_bf16(v.z, h.z, l.z);
        split_bf16(v.w, h.w, l.w);
        ((ushort4*)hi)[i] = h;
        ((ushort4*)lo)[i] = l;
    }
}

// ---------------------------------------------------------------------------
// Pack Wq (rows 0-511) + Wkv (rows 512-1535) into fused [L][1536][512] pair.
// ---------------------------------------------------------------------------
__global__ __launch_bounds__(256) void packqkv(
    const float* __restrict__ Wq, const float* __restrict__ Wkv,
    unsigned short* __restrict__ hi, unsigned short* __restrict__ lo)
{
    const int total = LL * 1536 * 128;          // float4 units
    int stride = gridDim.x * 256;
    for (int i = blockIdx.x * 256 + threadIdx.x; i < total; i += stride) {
        int l   = i / (1536 * 128);
        int rem = i - l * (1536 * 128);
        int n   = rem >> 7;
        int k4  = rem & 127;
        const float* src = (n < 512)
            ? Wq  + ((size_t)(l * 512 + n) * 512 + k4 * 4)
            : Wkv + ((size_t)(l * 1024 + (n - 512)) * 512 + k4 * 4);
        float4 v = *(const float4*)src;
        ushort4 h, s;
        split_bf16(v.x, h.x, s.x);
        split_bf16(v.y, h.y, s.y);
        split_bf16(v.z, h.z, s.z);
        split_bf16(v.w, h.w, s.w);
        ((ushort4*)hi)[i] = h;
        ((ushort4*)lo)[i] = s;
    }
}

// ---------------------------------------------------------------------------
// Embedding: h = word_emb[data] + pos_emb ; also emits bf16 hi/lo pair.
// ---------------------------------------------------------------------------
__global__ __launch_bounds__(256) void embed_kernel(
    const int* __restrict__ data, const float* __restrict__ we,
    const float* __restrict__ pe, float* __restrict__ h,
    unsigned short* __restrict__ hhi, unsigned short* __restrict__ hlo)
{
    int tok = blockIdx.x;
    int tid = threadIdx.x;
    int idx = data[tok];
    int s = tok & (SS - 1);
    size_t base = (size_t)tok * DD;
    size_t wb = (size_t)idx * DD;
    size_t pb = (size_t)s * DD;
    float a = we[wb + tid] + pe[pb + tid];
    float b = we[wb + 256 + tid] + pe[pb + 256 + tid];
    h[base + tid] = a;
    h[base + 256 + tid] = b;
    unsigned short hx, lx;
    split_bf16(a, hx, lx); hhi[base + tid] = hx;       hlo[base + tid] = lx;
    split_bf16(b, hx, lx); hhi[base + 256 + tid] = hx; hlo[base + 256 + tid] = lx;
}

// ---------------------------------------------------------------------------
// Split-bf16 MFMA GEMM: C[M,N] = A[M,K] * W[N,K]^T (+bias)(+relu)
// Block tile 128 x BN, 4 waves (2x2), wave tile 64 x BN/2,
// fragments 32x32 via v_mfma_f32_32x32x16_bf16 (3 MFMA per fragment pair).
// LDS: A-hi 16K | A-lo 16K | B-hi BT | B-lo BT; within each buffer:
// byte = slot*(rows*16) + ((row^slot)<<4)  (slot-major, XOR swizzle; 0 conf).
// Staging: REGISTER staged, async-STAGE split; DEEP=2 adds a second
// in-flight tile (ping-pong r0/r1) for 1-block/CU launches.
// EPI: 0 fp32, 1 fp32+bias, 2 bias+relu->pair, 3 pair,
//      5 fused qkv: n<512 -> q pair *0.125; <1024 -> K pair; else Vt pair.
// SWZ: serpentine n-chunk XCD remap - ONLY valid for grid (79,32) (logits).
// ---------------------------------------------------------------------------
template<int BN, int EPI, bool SWZ, int DEEP>
__global__ __launch_bounds__(256) void gemm_mfma(
    const unsigned short* __restrict__ Ahp, const unsigned short* __restrict__ Alp,
    const unsigned short* __restrict__ Whp, const unsigned short* __restrict__ Wlp,
    const float* __restrict__ bias, float* __restrict__ C,
    unsigned short* __restrict__ Chp, unsigned short* __restrict__ Clp,
    unsigned short* __restrict__ Khp, unsigned short* __restrict__ Klp,
    unsigned short* __restrict__ Vhp, unsigned short* __restrict__ Vlp,
    int N, int K)
{
    constexpr int FN  = BN / 64;           // n-fragments per wave
    constexpr int BT  = BN * 128;          // bytes per B tile (8 slots * BN * 16)
    constexpr int NBG = BN / 8;            // 8-row staging groups per B tile
    constexpr int NGRP = 32 + 2 * NBG;     // total staging groups per K-step
    constexpr int PW  = NGRP / 4;          // groups per wave
    __shared__ __align__(16) char smem[32768 + 2 * BT];  // Ah|Al|Bh|Bl

    int bx = blockIdx.x, by = blockIdx.y;
    if (SWZ) {
        // grid = (79, 32). XCD residue class x gets t in [x*316, x*316+316):
        // serpentine order = for n-chunk (7x10 + 1x9 panels): for band in 32:
        // for panel in chunk. W chunk (~2.6 MB pair) stays L2-resident per XCD.
        int id = by * 79 + bx;
        int t  = (id & 7) * 316 + (id >> 3);
        if (t < 2240) { int c = t / 320, r = t - c * 320; by = r / 10; bx = c * 10 + r % 10; }
        else          { int r = t - 2240;                 by = r / 9;  bx = 70 + r % 9; }
    }

    const int tid   = threadIdx.x;
    const int lane  = tid & 63;
    const int wid   = tid >> 6;
    const int wm    = wid >> 1;
    const int wn    = wid & 1;
    const int laneM = lane & 31;
    const int laneK = lane >> 5;
    const int m0    = by * 128;
    const int n0    = bx * BN;
    const int srow8 = lane >> 3;           // row-within-group for staging
    const int sslot = lane & 7;            // k-chunk (8 bf16) for staging

    // Precomputed k-invariant staging addresses: element offsets from Ahp.
    const int dAl = (int)(Alp - Ahp);
    const int dW  = (int)(Whp - Ahp);
    const int dWl = (int)(Wlp - Ahp);
    int offs[PW];
    int ldso[PW];
    #pragma unroll
    for (int t = 0; t < PW; ++t) {
        int g = wid * PW + t;
        if (g < 32) {                      // A: groups 0-15 hi, 16-31 lo
            int row = (g & 15) * 8 + srow8;
            offs[t] = (g < 16 ? 0 : dAl) + (m0 + row) * K + sslot * 8;
            ldso[t] = ((g >> 4) << 14) + sslot * 2048 + ((row ^ sslot) << 4);
        } else {                           // B: NBG groups hi, NBG lo
            int d = g - 32;
            int row = (d & (NBG - 1)) * 8 + srow8;
            int n = n0 + row;
            n = (n < N) ? n : (N - 1);     // clamp (logits tail); stores guarded
            offs[t] = (d < NBG ? dW : dWl) + n * K + sslot * 8;
            ldso[t] = 32768 + ((d < NBG) ? 0 : BT)
                    + sslot * (BN * 16) + ((row ^ sslot) << 4);
        }
    }

    f32x16 acc[2][FN];
    #pragma unroll
    for (int i = 0; i < 2; ++i)
        #pragma unroll
        for (int j = 0; j < FN; ++j)
            #pragma unroll
            for (int r = 0; r < 16; ++r) acc[i][j][r] = 0.f;

    auto loadt = [&](bhalf8* rb, int k) {
        #pragma unroll
        for (int t = 0; t < PW; ++t)
            rb[t] = *(const bhalf8*)(Ahp + offs[t] + k);
    };
    auto stage = [&](const bhalf8* rb) {
        #pragma unroll
        for (int t = 0; t < PW; ++t)
            *(bhalf8*)(smem + ldso[t]) = rb[t];
    };
    auto mfma_step = [&]() {
        #pragma unroll
        for (int kb = 0; kb < 4; ++kb) {   // 4 x (k=16) per K-step
            const int slot = kb * 2 + laneK;
            bhalf8 ah[2], al[2], bh[FN], bl[FN];
            #pragma unroll
            for (int i = 0; i < 2; ++i) {
                int row = wm * 64 + i * 32 + laneM;
                int off = slot * 2048 + ((row ^ slot) << 4);
                ah[i] = *(const bhalf8*)(smem + off);
                al[i] = *(const bhalf8*)(smem + 16384 + off);
            }
            #pragma unroll
            for (int j = 0; j < FN; ++j) {
                int row = wn * (BN / 2) + j * 32 + laneM;
                int off = 32768 + slot * (BN * 16) + ((row ^ slot) << 4);
                bh[j] = *(const bhalf8*)(smem + off);
                bl[j] = *(const bhalf8*)(smem + BT + off);
            }
            #pragma unroll
            for (int i = 0; i < 2; ++i)
                #pragma unroll
                for (int j = 0; j < FN; ++j) {
                    acc[i][j] = __builtin_amdgcn_mfma_f32_32x32x16_bf16(ah[i], bh[j], acc[i][j], 0, 0, 0);
                    acc[i][j] = __builtin_amdgcn_mfma_f32_32x32x16_bf16(ah[i], bl[j], acc[i][j], 0, 0, 0);
                    acc[i][j] = __builtin_amdgcn_mfma_f32_32x32x16_bf16(al[i], bh[j], acc[i][j], 0, 0, 0);
                }
        }
    };

    bhalf8 r0[PW], r1[DEEP == 2 ? PW : 1];
    loadt(r0, 0);
    if (DEEP == 2) loadt(r1, 64);

    if (DEEP == 1) {
        for (int k0 = 0; k0 < K; k0 += 64) {
            __syncthreads();               // previous tile's LDS reads done
            stage(r0);
            __syncthreads();               // staging visible
            if (k0 + 64 < K) loadt(r0, k0 + 64);
            mfma_step();
        }
    } else {
        for (int k0 = 0; k0 < K; k0 += 128) {
            __syncthreads();
            stage(r0);
            __syncthreads();
            if (k0 + 128 < K) loadt(r0, k0 + 128);
            mfma_step();
            __syncthreads();
            stage(r1);
            __syncthreads();
            if (k0 + 192 < K) loadt(r1, k0 + 192);
            mfma_step();
        }
    }

    // Epilogue. C/D layout: col = lane&31, row = (r&3)+8*(r>>2)+4*laneK
    #pragma unroll
    for (int j = 0; j < FN; ++j) {
        int ncol = n0 + wn * (BN / 2) + j * 32 + laneM;
        bool nok = (ncol < N);
        float bv = 0.f;
        if (EPI == 1 || EPI == 2) { if (nok) bv = bias[ncol]; }
        #pragma unroll
        for (int i = 0; i < 2; ++i) {
            #pragma unroll
            for (int r = 0; r < 16; ++r) {
                int mrow = m0 + wm * 64 + i * 32 + (r & 3) + ((r >> 2) << 3) + laneK * 4;
                float v = acc[i][j][r] + bv;
                if (EPI == 2) v = fmaxf(v, 0.f);
                if (nok) {
                    if (EPI == 2 || EPI == 3) {
                        unsigned short hx, lx;
                        split_bf16(v, hx, lx);
                        Chp[(size_t)mrow * N + ncol] = hx;
                        Clp[(size_t)mrow * N + ncol] = lx;
                    } else if (EPI == 5) {
                        unsigned short hx, lx;
                        if (ncol < 512) {             // q, pre-scaled (exact)
                            split_bf16(v * 0.125f, hx, lx);
                            Chp[(size_t)mrow * 512 + ncol] = hx;
                            Clp[(size_t)mrow * 512 + ncol] = lx;
                        } else if (ncol < 1024) {     // K
                            split_bf16(v, hx, lx);
                            Khp[(size_t)mrow * 512 + (ncol - 512)] = hx;
                            Klp[(size_t)mrow * 512 + (ncol - 512)] = lx;
                        } else {                      // V transposed
                            split_bf16(v, hx, lx);
                            Vhp[(size_t)(ncol - 1024) * TT + mrow] = hx;
                            Vlp[(size_t)(ncol - 1024) * TT + mrow] = lx;
                        }
                    } else {
                        C[(size_t)mrow * N + ncol] = v;
                    }
                }
            }
        }
    }
}

// ---------------------------------------------------------------------------
// MFMA flash attention (split-bf16, causal). One block = 64 q-rows x (head,b),
// 128 threads = 2 waves; wave wq owns q-rows [32*wq, 32*wq+32).
// Swapped QK^T: s = mfma(K, Q) -> C[key][q], col = q = lane&31 -> each lane
// holds 32 keys of ONE q-row; softmax stats are per-lane scalars + one
// shfl_xor(32). P transposed via per-wave LDS, RTZ-split, PV = mfma(Vt, P).
// LDS: K hi/lo + Vt hi/lo (XOR-swizzled, conflict-free b128) + P per wave.
// Q arrives pre-scaled by 0.125 (fused-qkv epilogue).
// ---------------------------------------------------------------------------
__global__ __launch_bounds__(128) void flash_mfma(
    const unsigned short* __restrict__ qhp, const unsigned short* __restrict__ qlp,
    const unsigned short* __restrict__ khp, const unsigned short* __restrict__ klp,
    const unsigned short* __restrict__ vthp, const unsigned short* __restrict__ vtlp,
    unsigned short* __restrict__ avh, unsigned short* __restrict__ avl)
{
    __shared__ __align__(16) char lds[50176];   // K 16K | Vt 16K | P 2x8704

    const int qt  = 15 - (int)blockIdx.x;       // heavy q-tiles first
    const int hh  = blockIdx.y;
    const int b   = blockIdx.z;
    const int tid = threadIdx.x;
    const int lane  = tid & 63;
    const int wq    = tid >> 6;
    const int laneM = lane & 31;
    const int laneK = lane >> 5;
    const int q0    = qt * 64;

    // Q fragments (B-operand): col q = laneM, k(d) = 16*ks + 8*laneK + i
    bhalf8 Qh[4], Ql[4];
    {
        size_t qoff = (size_t)(b * SS + q0 + 32 * wq + laneM) * 512 + hh * 64 + 8 * laneK;
        #pragma unroll
        for (int ks = 0; ks < 4; ++ks) {
            Qh[ks] = *(const bhalf8*)(qhp + qoff + 16 * ks);
            Ql[ks] = *(const bhalf8*)(qlp + qoff + 16 * ks);
        }
    }

    f32x16 O0, O1;                              // O^T frags: d-blocks 0,1
    #pragma unroll
    for (int r = 0; r < 16; ++r) { O0[r] = 0.f; O1[r] = 0.f; }
    float mrun = -1e30f, lrun = 0.f;            // per-lane (q = laneM)

    const int srow  = tid >> 1;                 // 0..63 staging row
    const int shalf = tid & 1;                  // 32-elem half
    float* Pl = (float*)(lds + 32768 + wq * 8704);   // [32 q][68]

    for (int kt = 0; kt <= qt; ++kt) {
        __syncthreads();                        // prev-tile LDS reads done
        {
            size_t kbase = (size_t)(b * SS + kt * 64 + srow) * 512 + hh * 64 + 32 * shalf;
            size_t vbase = (size_t)(hh * 64 + srow) * TT + b * SS + kt * 64 + 32 * shalf;
            bhalf8 k0[4], k1[4], v0[4], v1[4];
            #pragma unroll
            for (int j = 0; j < 4; ++j) {
                k0[j] = *(const bhalf8*)(khp  + kbase + 8 * j);
                k1[j] = *(const bhalf8*)(klp  + kbase + 8 * j);
                v0[j] = *(const bhalf8*)(vthp + vbase + 8 * j);
                v1[j] = *(const bhalf8*)(vtlp + vbase + 8 * j);
            }
            int ob = srow * 128 + 64 * shalf;
            int sw = (srow & 7) << 4;
            #pragma unroll
            for (int j = 0; j < 4; ++j) {
                int o = (ob + 16 * j) ^ sw;
                *(bhalf8*)(lds + o)         = k0[j];
                *(bhalf8*)(lds + 8192 + o)  = k1[j];
                *(bhalf8*)(lds + 16384 + o) = v0[j];
                *(bhalf8*)(lds + 24576 + o) = v1[j];
            }
        }
        __syncthreads();                        // tiles staged

        // S^T = K Q^T  (frag s0: keys 0-31, s1: keys 32-63; col = q)
        f32x16 s0, s1;
        #pragma unroll
        for (int r = 0; r < 16; ++r) { s0[r] = 0.f; s1[r] = 0.f; }
        __builtin_amdgcn_s_setprio(1);
        #pragma unroll
        for (int ks = 0; ks < 4; ++ks) {
            int db = 32 * ks + 16 * laneK;
            int o0 = (laneM * 128 + db) ^ ((laneM & 7) << 4);
            int r1 = 32 + laneM;
            int o1 = (r1 * 128 + db) ^ ((r1 & 7) << 4);
            bhalf8 kh0 = *(const bhalf8*)(lds + o0);
            bhalf8 kl0 = *(const bhalf8*)(lds + 8192 + o0);
            bhalf8 kh1 = *(const bhalf8*)(lds + o1);
            bhalf8 kl1 = *(const bhalf8*)(lds + 8192 + o1);
            s0 = __builtin_amdgcn_mfma_f32_32x32x16_bf16(kh0, Qh[ks], s0, 0, 0, 0);
            s0 = __builtin_amdgcn_mfma_f32_32x32x16_bf16(kh0, Ql[ks], s0, 0, 0, 0);
            s0 = __builtin_amdgcn_mfma_f32_32x32x16_bf16(kl0, Qh[ks], s0, 0, 0, 0);
            s1 = __builtin_amdgcn_mfma_f32_32x32x16_bf16(kh1, Qh[ks], s1, 0, 0, 0);
            s1 = __builtin_amdgcn_mfma_f32_32x32x16_bf16(kh1, Ql[ks], s1, 0, 0, 0);
            s1 = __builtin_amdgcn_mfma_f32_32x32x16_bf16(kl1, Qh[ks], s1, 0, 0, 0);
        }
        __builtin_amdgcn_s_setprio(0);

        if (kt == qt) {                         // causal mask on diagonal tile
            int qrel = 32 * wq + laneM;
            #pragma unroll
            for (int r = 0; r < 16; ++r) {
                int krel = (r & 3) + ((r >> 2) << 3) + 4 * laneK;
                if (krel > qrel)      s0[r] = -1e30f;
                if (krel + 32 > qrel) s1[r] = -1e30f;
            }
        }

        // online softmax, per-lane scalars (lane = one q-row, 32 of 64 keys;
        // partner lane^32 holds the other 32)
        float mx = s0[0];
        #pragma unroll
        for (int r = 1; r < 16; ++r) mx = fmaxf(mx, s0[r]);
        #pragma unroll
        for (int r = 0; r < 16; ++r) mx = fmaxf(mx, s1[r]);
        mx = fmaxf(mx, __shfl_xor(mx, 32));
        float mn = fmaxf(mrun, mx);
        float alpha = __expf(mrun - mn);
        mrun = mn;
        float rs = 0.f;
        #pragma unroll
        for (int r = 0; r < 16; ++r) {
            float p0 = __expf(s0[r] - mn);
            float p1 = __expf(s1[r] - mn);
            s0[r] = p0; s1[r] = p1;
            rs += p0 + p1;
        }
        rs += __shfl_xor(rs, 32);
        lrun = lrun * alpha + rs;
        #pragma unroll
        for (int r = 0; r < 16; ++r) { O0[r] *= alpha; O1[r] *= alpha; }

        // P^T -> LDS as [q][key]
        #pragma unroll
        for (int r = 0; r < 16; ++r) {
            int krel = (r & 3) + ((r >> 2) << 3) + 4 * laneK;
            Pl[laneM * 68 + krel]      = s0[r];
            Pl[laneM * 68 + 32 + krel] = s1[r];
        }
        __asm__ volatile("s_waitcnt lgkmcnt(0)" ::: "memory");
        __builtin_amdgcn_sched_barrier(0);

        // O^T += Vt P^T
        #pragma unroll
        for (int ks = 0; ks < 4; ++ks) {
            const float* pr = &Pl[laneM * 68 + 16 * ks + 8 * laneK];
            float4 pa = *(const float4*)pr;
            float4 pb = *(const float4*)(pr + 4);
            float pv[8] = {pa.x, pa.y, pa.z, pa.w, pb.x, pb.y, pb.z, pb.w};
            bhalf8 ph, plo;                     // RTZ split (P >= 0)
            #pragma unroll
            for (int i = 0; i < 8; ++i) {
                unsigned u = __float_as_uint(pv[i]);
                ph[i] = (short)(u >> 16);
                float lf = pv[i] - __uint_as_float(u & 0xFFFF0000u);
                plo[i] = (short)(__float_as_uint(lf) >> 16);
            }
            int db = 32 * ks + 16 * laneK;
            __builtin_amdgcn_s_setprio(1);
            {
                int col = laneM;
                int o = (col * 128 + db) ^ ((col & 7) << 4);
                bhalf8 vh = *(const bhalf8*)(lds + 16384 + o);
                bhalf8 vl = *(const bhalf8*)(lds + 24576 + o);
                O0 = __builtin_amdgcn_mfma_f32_32x32x16_bf16(vh, ph,  O0, 0, 0, 0);
                O0 = __builtin_amdgcn_mfma_f32_32x32x16_bf16(vl, ph,  O0, 0, 0, 0);
                O0 = __builtin_amdgcn_mfma_f32_32x32x16_bf16(vh, plo, O0, 0, 0, 0);
            }
            {
                int col = 32 + laneM;
                int o = (col * 128 + db) ^ ((col & 7) << 4);
                bhalf8 vh = *(const bhalf8*)(lds + 16384 + o);
                bhalf8 vl = *(const bhalf8*)(lds + 24576 + o);
                O1 = __builtin_amdgcn_mfma_f32_32x32x16_bf16(vh, ph,  O1, 0, 0, 0);
                O1 = __builtin_amdgcn_mfma_f32_32x32x16_bf16(vl, ph,  O1, 0, 0, 0);
                O1 = __builtin_amdgcn_mfma_f32_32x32x16_bf16(vh, plo, O1, 0, 0, 0);
            }
            __builtin_amdgcn_s_setprio(0);
        }
    }

    // Epilogue: transpose O^T through per-wave LDS, coalesced bf16-pair store
    float inv = 1.0f / lrun;
    #pragma unroll
    for (int r = 0; r < 16; ++r) {
        int d = (r & 3) + ((r >> 2) << 3) + 4 * laneK;
        Pl[laneM * 68 + d]      = O0[r] * inv;
        Pl[laneM * 68 + 32 + d] = O1[r] * inv;
    }
    __asm__ volatile("s_waitcnt lgkmcnt(0)" ::: "memory");
    __builtin_amdgcn_sched_barrier(0);
    #pragma unroll
    for (int it = 0; it < 16; ++it) {
        int qr = it * 2 + (lane >> 5);          // q-row within wave band
        int d  = (lane & 31) * 2;
        float2 v = *(const float2*)&Pl[qr * 68 + d];
        unsigned short h0, l0, h1, l1;
        split_bf16(v.x, h0, l0);
        split_bf16(v.y, h1, l1);
        size_t base = (size_t)(b * SS + q0 + 32 * wq + qr) * 512 + hh * 64 + d;
        ushort2 hv; hv.x = h0; hv.y = h1;
        ushort2 lv; lv.x = l0; lv.y = l1;
        *(ushort2*)(avh + base) = hv;
        *(ushort2*)(avl + base) = lv;
    }
}

// ---------------------------------------------------------------------------
// Fused residual-add + LayerNorm; also emits bf16 hi/lo pair of the output.
// ---------------------------------------------------------------------------
__global__ __launch_bounds__(256) void add_ln_kernel(
    float* __restrict__ h, const float* __restrict__ x,
    const float* __restrict__ g, const float* __restrict__ bta,
    unsigned short* __restrict__ hhi, unsigned short* __restrict__ hlo)
{
    int tok = blockIdx.x, tid = threadIdx.x;
    size_t base = (size_t)tok * DD;
    float v0 = h[base + tid] + x[base + tid];
    float v1 = h[base + 256 + tid] + x[base + 256 + tid];

    __shared__ float rs[256], rq[256];
    rs[tid] = v0 + v1;
    rq[tid] = v0 * v0 + v1 * v1;
    __syncthreads();
    for (int off = 128; off > 0; off >>= 1) {
        if (tid < off) { rs[tid] += rs[tid + off]; rq[tid] += rq[tid + off]; }
        __syncthreads();
    }
    float mean = rs[0] * (1.f / 512.f);
    float var  = rq[0] * (1.f / 512.f) - mean * mean;
    float inv  = rsqrtf(var + 1e-5f);
    float o0 = (v0 - mean) * inv * g[tid]       + bta[tid];
    float o1 = (v1 - mean) * inv * g[256 + tid] + bta[256 + tid];
    h[base + tid]       = o0;
    h[base + 256 + tid] = o1;
    unsigned short a, b;
    split_bf16(o0, a, b); hhi[base + tid]       = a; hlo[base + tid]       = b;
    split_bf16(o1, a, b); hhi[base + 256 + tid] = a; hlo[base + 256 + tid] = b;
}

// ---------------------------------------------------------------------------
extern "C" void kernel_launch(void* const* d_in, const int* in_sizes, int n_in,
                              void* d_out, int out_size, void* d_ws, size_t ws_size,
                              hipStream_t stream)
{
    const int*   data = (const int*)d_in[0];
    const float* we   = (const float*)d_in[1];   // word_emb [V, D]
    const float* pe   = (const float*)d_in[2];   // pos_emb
    const float* Wq   = (const float*)d_in[3];   // [L, 512, 512]
    const float* Wkv  = (const float*)d_in[4];   // [L, 1024, 512]
    const float* Wo   = (const float*)d_in[5];   // [L, 512, 512]
    const float* g1   = (const float*)d_in[6];
    const float* bl1  = (const float*)d_in[7];
    const float* W1   = (const float*)d_in[8];   // [L, 2048, 512]
    const float* b1   = (const float*)d_in[9];
    const float* W2   = (const float*)d_in[10];  // [L, 512, 2048]
    const float* b2   = (const float*)d_in[11];
    const float* g2   = (const float*)d_in[12];
    const float* bl2  = (const float*)d_in[13];
    const float* outb = (const float*)d_in[14];  // [V]
    float* out = (float*)d_out;

    typedef unsigned short us;
    // Workspace layout (~227 MB). Activations FIRST, weights AFTER
    // (gemm staging uses positive int offsets from its A pointer).
    float* h    = (float*)d_ws;                          // TT*512 f32
    us* qhp  = (us*)(h + (size_t)TT * 512);              // 8 x (TT*512 us) block
    us* qlp  = qhp  + (size_t)TT * 512;
    us* khp  = qlp  + (size_t)TT * 512;
    us* klp  = khp  + (size_t)TT * 512;
    us* vthp = klp  + (size_t)TT * 512;
    us* vtlp = vthp + (size_t)TT * 512;
    us* avh  = vtlp + (size_t)TT * 512;
    us* avl  = avh  + (size_t)TT * 512;
    float* tmp = (float*)(avl + (size_t)TT * 512);       // TT*512 f32
    us* hhi  = (us*)(tmp + (size_t)TT * 512);
    us* hlo  = hhi + (size_t)TT * 512;
    // ff pair aliases the q..av block (dead when ff is live): 2 x TT*2048 us
    us* ffh = qhp;
    us* ffl = qhp + (size_t)TT * 2048;
    // pre-converted weights (bf16 hi/lo); qkv fused [L][1536][512]
    us* wqkvh = hlo  + (size_t)TT * 512;
    us* wqkvl = wqkvh + (size_t)LL * 1536 * 512;
    us* woh  = wqkvl + (size_t)LL * 1536 * 512;
    us* wol  = woh  + (size_t)LL * 512 * 512;
    us* w1h  = wol  + (size_t)LL * 512 * 512;
    us* w1l  = w1h  + (size_t)LL * 2048 * 512;
    us* w2h  = w1l  + (size_t)LL * 2048 * 512;
    us* w2l  = w2h  + (size_t)LL * 512 * 2048;
    us* weh  = w2l  + (size_t)LL * 512 * 2048;
    us* wel  = weh  + (size_t)VV * 512;

    auto cv = [&](const float* s, us* hh, us* ll, size_t n) {
        int n4 = (int)(n >> 2);
        int blocks = (n4 + 255) / 256;
        if (blocks > 2048) blocks = 2048;
        convsplit<<<blocks, 256, 0, stream>>>(s, hh, ll, n4);
    };
    packqkv<<<2048, 256, 0, stream>>>(Wq, Wkv, wqkvh, wqkvl);
    cv(Wo,  woh,  wol,  (size_t)LL * 512 * 512);
    cv(W1,  w1h,  w1l,  (size_t)LL * 2048 * 512);
    cv(W2,  w2h,  w2l,  (size_t)LL * 512 * 2048);
    cv(we,  weh,  wel,  (size_t)VV * 512);

    embed_kernel<<<TT, 256, 0, stream>>>(data, we, pe, h, hhi, hlo);

    for (int l = 0; l < LL; ++l) {
        const us* lwqkvh = wqkvh + (size_t)l * 1536 * 512;
        const us* lwqkvl = wqkvl + (size_t)l * 1536 * 512;
        const us* lwoh  = woh  + (size_t)l * 512 * 512;
        const us* lwol  = wol  + (size_t)l * 512 * 512;
        const us* lw1h  = w1h  + (size_t)l * 2048 * 512;
        const us* lw1l  = w1l  + (size_t)l * 2048 * 512;
        const us* lw2h  = w2h  + (size_t)l * 512 * 2048;
        const us* lw2l  = w2l  + (size_t)l * 512 * 2048;

        // fused q+k+v projection: N=1536, 768 blocks = 3/CU resident
        gemm_mfma<64, 5, false, 1><<<dim3(24, 32), 256, 0, stream>>>(
            hhi, hlo, lwqkvh, lwqkvl, nullptr, nullptr,
            qhp, qlp, khp, klp, vthp, vtlp, 1536, 512);
        flash_mfma<<<dim3(16, HH, BB), 128, 0, stream>>>(
            qhp, qlp, khp, klp, vthp, vtlp, avh, avl);
        gemm_mfma<64, 0, false, 2><<<dim3(8, 32), 256, 0, stream>>>(
            avh, avl, lwoh, lwol, nullptr, tmp,
            nullptr, nullptr, nullptr, nullptr, nullptr, nullptr, 512, 512);
        add_ln_kernel<<<TT, 256, 0, stream>>>(h, tmp, g1 + l * 512, bl1 + l * 512, hhi, hlo);
        gemm_mfma<128, 2, false, 1><<<dim3(16, 32), 256, 0, stream>>>(
            hhi, hlo, lw1h, lw1l, b1 + l * 2048, nullptr,
            ffh, ffl, nullptr, nullptr, nullptr, nullptr, 2048, 512);
        gemm_mfma<64, 1, false, 2><<<dim3(8, 32), 256, 0, stream>>>(
            ffh, ffl, lw2h, lw2l, b2 + l * 512, tmp,
            nullptr, nullptr, nullptr, nullptr, nullptr, nullptr, 512, 2048);
        add_ln_kernel<<<TT, 256, 0, stream>>>(h, tmp, g2 + l * 512, bl2 + l * 512, hhi, hlo);
    }

    // logits = h @ word_emb^T + out_b (tied), N = 10000, serpentine XCD swizzle
    gemm_mfma<128, 1, true, 1><<<dim3((VV + 127) / 128, 32), 256, 0, stream>>>(
        hhi, hlo, weh, wel, outb, out,
        nullptr, nullptr, nullptr, nullptr, nullptr, nullptr, VV, 512);
}